// Round 12
// baseline (1412.032 us; speedup 1.0000x reference)
//
#include <hip/hip_runtime.h>
#include <hip/hip_fp16.h>

#define NPTS 500000
#define RPLANE 128
#define FDIM 32
#define PLSZ (RPLANE * RPLANE * FDIM)
#define NGROUPS 31250         // 500000 / 16
#define TOTWAVES 4096         // 256 blocks x 16 waves

typedef __bf16 bfx8 __attribute__((ext_vector_type(8)));
typedef float f32x4 __attribute__((ext_vector_type(4)));

__device__ __forceinline__ unsigned short f2bf(float f) {
    unsigned int u = __builtin_bit_cast(unsigned int, f);
    unsigned int r = (u + 0x7FFFu + ((u >> 16) & 1u)) >> 16;
    return (unsigned short)r;
}

__device__ __forceinline__ unsigned pk2(float a, float b) {
    return (unsigned)f2bf(a) | ((unsigned)f2bf(b) << 16);
}

__device__ __forceinline__ __half2 u2h(unsigned u) {
    return __builtin_bit_cast(__half2, u);
}

__device__ __forceinline__ bfx8 asfrag(uint4 v) {
    return __builtin_bit_cast(bfx8, v);
}

// Prep: weight frags (zero-shuffle hidden permutation for wenc/w1 output
// columns: u(ct,i) = 32*(ct>>1)+8*(i>>2)+4*(ct&1)+(i&3); w2 natural) +
// fp16 plane cache (vectorized).
__global__ void prep3(const float* __restrict__ wenc, const float* __restrict__ w1,
                      const float* __restrict__ w2, const float* __restrict__ spf,
                      const float* __restrict__ tpf,
                      unsigned short* __restrict__ wf, __half* __restrict__ ph) {
    const int WTOT = 86016;
    const int PHALF = 3 * PLSZ;           // pairs
    const int total = WTOT + PHALF;
    for (int i = blockIdx.x * blockDim.x + threadIdx.x; i < total;
         i += gridDim.x * blockDim.x) {
        if (i < WTOT) {
            int j = i & 7;
            int l = (i >> 3) & 63;
            int m = l & 15;
            if (i < 8192) {
                int ct = i >> 9;
                int k = ((l >> 4) << 3) + j;
                int u = 32 * (ct >> 1) + ((m >> 2) << 3) + 4 * (ct & 1) + (m & 3);
                wf[i] = f2bf(wenc[(size_t)k * 256 + u]);
            } else if (i < 73728) {
                int idx = i - 8192;
                int b = idx >> 9;
                int ct = b >> 3, ks = b & 7;
                int k = ks * 32 + ((l >> 4) << 3) + j;
                int u = 32 * (ct >> 1) + ((m >> 2) << 3) + 4 * (ct & 1) + (m & 3);
                wf[i] = f2bf(w1[(size_t)k * 256 + u]);
            } else {
                int idx = i - 73728;
                int b = idx >> 9;
                int ct = b >> 3, ks = b & 7;
                int k = ks * 32 + ((l >> 4) << 3) + j;
                int col = ct * 16 + m;
                wf[i] = f2bf(w2[(size_t)k * 48 + col]);
            }
        } else {
            int j2 = (i - WTOT) * 2;
            const float* src = (j2 < 3 * PLSZ) ? spf + j2 : tpf + (j2 - 3 * PLSZ);
            float2 v = *(const float2*)src;
            *(__half2*)(ph + j2) = __floats2half2_rn(v.x, v.y);
        }
    }
}

// Single fused kernel: 1024 threads (16 waves) per block, w1+w2 frags in LDS.
// Each wave-pass handles one 16-point group end-to-end: passthrough copies,
// plane gather -> act1 regs, 3 MFMA layers (zero-shuffle packing), store.
__global__ __launch_bounds__(1024, 1) void fused6(
    const float* __restrict__ rays, const float* __restrict__ tme,
    const float* __restrict__ rot, const float* __restrict__ h_e,
    const float* __restrict__ shs, const __half* __restrict__ ph,
    const unsigned short* __restrict__ wf,
    const float* __restrict__ benc, const float* __restrict__ b1v,
    const float* __restrict__ b2v, float* __restrict__ out) {
    __shared__ unsigned short wlds[77824];   // w1 [0,65536) + w2 [65536,77824)
    const int tid = threadIdx.x;
    for (int i = tid * 8; i < 77824; i += 1024 * 8)
        *(uint4*)&wlds[i] = *(const uint4*)(wf + 8192 + i);
    __syncthreads();

    const int wid = tid >> 6;
    const int lane = tid & 63;
    const int g = lane >> 4;
    const int c = lane & 15;
    const int wglob = blockIdx.x * 16 + wid;

    for (int grp = wglob; grp < NGROUPS; grp += TOTWAVES) {
        const int p0 = grp * 16;

        // ---- passthrough: 48 + 64 + 16 floats, cooperative ----
        if (lane < 48) out[3 * p0 + lane] = rays[3 * p0 + lane];
        out[3 * NPTS + 4 * p0 + lane] = rot[4 * p0 + lane];
        if (lane < 16) out[7 * NPTS + p0 + lane] = h_e[2 * (p0 + lane)];

        // ---- gather: point p0+c, features 8g..8g+7 -> act1 (B-frag) ----
        const int p = p0 + c;
        float px = rays[p * 3 + 0], py = rays[p * 3 + 1], pz = rays[p * 3 + 2];
        const float inv = 0.625f;
        float xn = fminf(fmaxf(px * inv, -1.f), 1.f) * 0.5f + 0.5f;
        float yn = fminf(fmaxf(py * inv, -1.f), 1.f) * 0.5f + 0.5f;
        float zn = fminf(fmaxf(pz * inv, -1.f), 1.f) * 0.5f + 0.5f;
        float tt = fminf(fmaxf(tme[p], 0.f), 1.f);
        float c4[4] = {xn, yn, zn, tt};
        int i0[4];
        float fr[4];
#pragma unroll
        for (int cc = 0; cc < 4; ++cc) {
            float x = c4[cc] * 127.0f;
            float xf = fminf(floorf(x), 126.0f);
            i0[cc] = (int)xf;
            fr[cc] = x - xf;
        }
        const int uc[6] = {0, 0, 1, 0, 1, 2};
        const int vc[6] = {1, 2, 2, 3, 3, 3};
        __half2 g2[4];
#pragma unroll
        for (int pl = 0; pl < 6; ++pl) {
            int x0 = i0[uc[pl]], y0 = i0[vc[pl]];
            float fx = fr[uc[pl]], fy = fr[vc[pl]];
            const __half* base = ph + (size_t)pl * PLSZ + ((y0 * RPLANE + x0) << 5) + (g << 3);
            uint4 q00 = *(const uint4*)base;
            uint4 q01 = *(const uint4*)(base + FDIM);
            uint4 q10 = *(const uint4*)(base + RPLANE * FDIM);
            uint4 q11 = *(const uint4*)(base + RPLANE * FDIM + FDIM);
            __half2 wa = __float2half2_rn((1.f - fx) * (1.f - fy));
            __half2 wb = __float2half2_rn(fx * (1.f - fy));
            __half2 wc = __float2half2_rn((1.f - fx) * fy);
            __half2 wd = __float2half2_rn(fx * fy);
            unsigned qa[4] = {q00.x, q00.y, q00.z, q00.w};
            unsigned qb[4] = {q01.x, q01.y, q01.z, q01.w};
            unsigned qc[4] = {q10.x, q10.y, q10.z, q10.w};
            unsigned qd[4] = {q11.x, q11.y, q11.z, q11.w};
#pragma unroll
            for (int i = 0; i < 4; ++i) {
                __half2 r = __hmul2(u2h(qa[i]), wa);
                r = __hfma2(u2h(qb[i]), wb, r);
                r = __hfma2(u2h(qc[i]), wc, r);
                r = __hfma2(u2h(qd[i]), wd, r);
                g2[i] = (pl == 0) ? r : __hmul2(g2[i], r);
            }
        }
        uint4 a1v;
        {
            float2 v0 = __half22float2(g2[0]);
            float2 v1 = __half22float2(g2[1]);
            float2 v2 = __half22float2(g2[2]);
            float2 v3 = __half22float2(g2[3]);
            a1v.x = pk2(v0.x, v0.y);
            a1v.y = pk2(v1.x, v1.y);
            a1v.z = pk2(v2.x, v2.y);
            a1v.w = pk2(v3.x, v3.y);
        }
        bfx8 act1 = asfrag(a1v);

        // ---- layer 1: wenc frags (global, L1-hot); direct pack -> act2 ----
        uint4 act2[8];
#pragma unroll
        for (int ct = 0; ct < 16; ++ct) {
            uint4 cur = *(const uint4*)(wf + (size_t)ct * 512 + lane * 8);
            float4 b4 = *(const float4*)(benc + 32 * (ct >> 1) + 8 * g + 4 * (ct & 1));
            f32x4 z = {0.f, 0.f, 0.f, 0.f};
            f32x4 d = __builtin_amdgcn_mfma_f32_16x16x32_bf16(asfrag(cur), act1, z, 0, 0, 0);
            float v0 = fmaxf(d[0] + b4.x, 0.f);
            float v1 = fmaxf(d[1] + b4.y, 0.f);
            float v2 = fmaxf(d[2] + b4.z, 0.f);
            float v3 = fmaxf(d[3] + b4.w, 0.f);
            unsigned Q0 = pk2(v0, v1), Q1 = pk2(v2, v3);
            if ((ct & 1) == 0) {
                act2[ct >> 1].x = Q0; act2[ct >> 1].y = Q1;
            } else {
                act2[ct >> 1].z = Q0; act2[ct >> 1].w = Q1;
            }
        }

        // ---- layer 2: w1 frags from LDS (chunked 4); direct pack -> act3 ----
        uint4 act3[8];
#pragma unroll
        for (int ct = 0; ct < 16; ++ct) {
            f32x4 accA = {0.f, 0.f, 0.f, 0.f};
            f32x4 accB = {0.f, 0.f, 0.f, 0.f};
#pragma unroll
            for (int h2 = 0; h2 < 2; ++h2) {
                uint4 w0 = *(const uint4*)&wlds[(ct * 8 + h2 * 4 + 0) * 512 + lane * 8];
                uint4 w1r = *(const uint4*)&wlds[(ct * 8 + h2 * 4 + 1) * 512 + lane * 8];
                uint4 w2r = *(const uint4*)&wlds[(ct * 8 + h2 * 4 + 2) * 512 + lane * 8];
                uint4 w3 = *(const uint4*)&wlds[(ct * 8 + h2 * 4 + 3) * 512 + lane * 8];
                accA = __builtin_amdgcn_mfma_f32_16x16x32_bf16(asfrag(w0), asfrag(act2[h2 * 4 + 0]), accA, 0, 0, 0);
                accB = __builtin_amdgcn_mfma_f32_16x16x32_bf16(asfrag(w1r), asfrag(act2[h2 * 4 + 1]), accB, 0, 0, 0);
                accA = __builtin_amdgcn_mfma_f32_16x16x32_bf16(asfrag(w2r), asfrag(act2[h2 * 4 + 2]), accA, 0, 0, 0);
                accB = __builtin_amdgcn_mfma_f32_16x16x32_bf16(asfrag(w3), asfrag(act2[h2 * 4 + 3]), accB, 0, 0, 0);
            }
            f32x4 acc = accA + accB;
            float4 b4 = *(const float4*)(b1v + 32 * (ct >> 1) + 8 * g + 4 * (ct & 1));
            float v0 = fmaxf(acc[0] + b4.x, 0.f);
            float v1 = fmaxf(acc[1] + b4.y, 0.f);
            float v2 = fmaxf(acc[2] + b4.z, 0.f);
            float v3 = fmaxf(acc[3] + b4.w, 0.f);
            unsigned Q0 = pk2(v0, v1), Q1 = pk2(v2, v3);
            if ((ct & 1) == 0) {
                act3[ct >> 1].x = Q0; act3[ct >> 1].y = Q1;
            } else {
                act3[ct >> 1].z = Q0; act3[ct >> 1].w = Q1;
            }
        }

        // ---- layer 3: w2 frags from LDS; D[pt][outcol]; + b2 + shs -> out ----
#pragma unroll
        for (int ct = 0; ct < 3; ++ct) {
            f32x4 accA = {0.f, 0.f, 0.f, 0.f};
            f32x4 accB = {0.f, 0.f, 0.f, 0.f};
#pragma unroll
            for (int h2 = 0; h2 < 2; ++h2) {
                uint4 w0 = *(const uint4*)&wlds[65536 + (ct * 8 + h2 * 4 + 0) * 512 + lane * 8];
                uint4 w1r = *(const uint4*)&wlds[65536 + (ct * 8 + h2 * 4 + 1) * 512 + lane * 8];
                uint4 w2r = *(const uint4*)&wlds[65536 + (ct * 8 + h2 * 4 + 2) * 512 + lane * 8];
                uint4 w3 = *(const uint4*)&wlds[65536 + (ct * 8 + h2 * 4 + 3) * 512 + lane * 8];
                accA = __builtin_amdgcn_mfma_f32_16x16x32_bf16(asfrag(act3[h2 * 4 + 0]), asfrag(w0), accA, 0, 0, 0);
                accB = __builtin_amdgcn_mfma_f32_16x16x32_bf16(asfrag(act3[h2 * 4 + 1]), asfrag(w1r), accB, 0, 0, 0);
                accA = __builtin_amdgcn_mfma_f32_16x16x32_bf16(asfrag(act3[h2 * 4 + 2]), asfrag(w2r), accA, 0, 0, 0);
                accB = __builtin_amdgcn_mfma_f32_16x16x32_bf16(asfrag(act3[h2 * 4 + 3]), asfrag(w3), accB, 0, 0, 0);
            }
            f32x4 acc = accA + accB;
            float bias = b2v[16 * ct + c];
#pragma unroll
            for (int r = 0; r < 4; ++r) {
                int pp = p0 + 4 * g + r;
                size_t idx = (size_t)pp * 48 + 16 * ct + c;
                out[(size_t)NPTS * 8 + idx] = shs[idx] + acc[r] + bias;
            }
        }
    }
}

extern "C" void kernel_launch(void* const* d_in, const int* in_sizes, int n_in,
                              void* d_out, int out_size, void* d_ws, size_t ws_size,
                              hipStream_t stream) {
    const float* rays = (const float*)d_in[0];
    const float* rot  = (const float*)d_in[1];
    const float* shs  = (const float*)d_in[3];
    const float* tme  = (const float*)d_in[5];
    const float* h_e  = (const float*)d_in[6];
    const float* spf  = (const float*)d_in[7];
    const float* tpf  = (const float*)d_in[8];
    const float* wenc = (const float*)d_in[9];
    const float* benc = (const float*)d_in[10];
    const float* w1   = (const float*)d_in[11];
    const float* b1v  = (const float*)d_in[12];
    const float* w2   = (const float*)d_in[13];
    const float* b2v  = (const float*)d_in[14];
    float* out = (float*)d_out;
    unsigned short* wf = (unsigned short*)d_ws;    // 86016 shorts of weight frags
    __half* ph = (__half*)(wf + 86016);            // 6*PLSZ fp16 plane cache (~6.3 MB)

    prep3<<<2048, 256, 0, stream>>>(wenc, w1, w2, spf, tpf, wf, ph);
    fused6<<<256, 1024, 0, stream>>>(rays, tme, rot, h_e, shs, ph, wf,
                                     benc, b1v, b2v, out);
}

// Round 13
// 240.576 us; speedup vs baseline: 5.8694x; 5.8694x over previous
//
#include <hip/hip_runtime.h>
#include <hip/hip_fp16.h>

#define NPTS 500000
#define RPLANE 128
#define FDIM 32
#define PLSZ (RPLANE * RPLANE * FDIM)
#define NTILES 15625          // 500000 / 32
#define NWAVES 2048           // 256 blocks x 8 waves

typedef __bf16 bfx8 __attribute__((ext_vector_type(8)));
typedef float f32x4 __attribute__((ext_vector_type(4)));

__device__ __forceinline__ unsigned short f2bf(float f) {
    unsigned int u = __builtin_bit_cast(unsigned int, f);
    unsigned int r = (u + 0x7FFFu + ((u >> 16) & 1u)) >> 16;
    return (unsigned short)r;
}

__device__ __forceinline__ unsigned pk2(float a, float b) {
    return (unsigned)f2bf(a) | ((unsigned)f2bf(b) << 16);
}

__device__ __forceinline__ __half2 u2h(unsigned u) {
    return __builtin_bit_cast(__half2, u);
}

__device__ __forceinline__ bfx8 asfrag(uint4 v) {
    return __builtin_bit_cast(bfx8, v);
}

// D->act-frag conversion via ds_bpermute (proven fused5/mlp6 path).
__device__ __forceinline__ uint4 convD(unsigned e0, unsigned e1, unsigned o0,
                                       unsigned o1, int a0, int a1, bool sel) {
    uint4 W;
    int x, y;
    x = __builtin_amdgcn_ds_bpermute(a0, (int)e0);
    y = __builtin_amdgcn_ds_bpermute(a0, (int)o0);
    W.x = (unsigned)(sel ? y : x);
    x = __builtin_amdgcn_ds_bpermute(a0, (int)e1);
    y = __builtin_amdgcn_ds_bpermute(a0, (int)o1);
    W.y = (unsigned)(sel ? y : x);
    x = __builtin_amdgcn_ds_bpermute(a1, (int)e0);
    y = __builtin_amdgcn_ds_bpermute(a1, (int)o0);
    W.z = (unsigned)(sel ? y : x);
    x = __builtin_amdgcn_ds_bpermute(a1, (int)e1);
    y = __builtin_amdgcn_ds_bpermute(a1, (int)o1);
    W.w = (unsigned)(sel ? y : x);
    return W;
}

// Prep: weight frags (natural columns) + fp16 plane cache (vectorized pairs).
// Frag block b = ct*(K/32)+ks, lane l, elem j: W[k=ks*32+(l>>4)*8+j][col=ct*16+(l&15)].
__global__ void prep2(const float* __restrict__ wenc, const float* __restrict__ w1,
                      const float* __restrict__ w2, const float* __restrict__ spf,
                      const float* __restrict__ tpf,
                      unsigned short* __restrict__ wf, __half* __restrict__ ph) {
    const int WTOT = 86016;
    const int PHALF = 3 * PLSZ;           // fp16 pairs
    const int total = WTOT + PHALF;
    for (int i = blockIdx.x * blockDim.x + threadIdx.x; i < total;
         i += gridDim.x * blockDim.x) {
        if (i < WTOT) {
            const float* W;
            unsigned short* dst;
            int K, Ncols, idx;
            if (i < 8192)       { W = wenc; K = 32;  Ncols = 256; idx = i;         dst = wf; }
            else if (i < 73728) { W = w1;   K = 256; Ncols = 256; idx = i - 8192;  dst = wf + 8192; }
            else                { W = w2;   K = 256; Ncols = 48;  idx = i - 73728; dst = wf + 73728; }
            int j = idx & 7;
            int l = (idx >> 3) & 63;
            int b = idx >> 9;
            int KS = K >> 5;
            int ct = b / KS;
            int ks = b - ct * KS;
            int k = ks * 32 + ((l >> 4) << 3) + j;
            int col = ct * 16 + (l & 15);
            dst[idx] = f2bf(W[(size_t)k * Ncols + col]);
        } else {
            int j2 = (i - WTOT) * 2;
            const float* src = (j2 < 3 * PLSZ) ? spf + j2 : tpf + (j2 - 3 * PLSZ);
            float2 v = *(const float2*)src;
            *(__half2*)(ph + j2) = __floats2half2_rn(v.x, v.y);
        }
    }
}

// fused5 structure, 256 blocks x 8 waves, 8 tiles/wave (one LDS staging per
// CU), passthrough folded in. No barriers after staging.
__global__ __launch_bounds__(512, 2) void fused7(
    const float* __restrict__ rays, const float* __restrict__ tme,
    const float* __restrict__ rot, const float* __restrict__ h_e,
    const float* __restrict__ shs, const __half* __restrict__ ph,
    const unsigned short* __restrict__ wf,
    const float* __restrict__ benc, const float* __restrict__ b1v,
    const float* __restrict__ b2v, float* __restrict__ out) {
    __shared__ unsigned short wlds[77824];   // w1 frags [0,65536) + w2 frags [65536,77824)
    const int tid = threadIdx.x;
    const int wid = tid >> 6;
    const int lane = tid & 63;

    // ---- stage w1+w2 frags global->LDS (linear copy), one barrier ----
#pragma unroll
    for (int i = tid * 8; i < 77824; i += 512 * 8)
        *(uint4*)&wlds[i] = *(const uint4*)(wf + 8192 + i);
    __syncthreads();

    const int g = lane >> 4;
    const int c = lane & 15;
    const int a0 = 4 * (32 * (g & 1) + c);   // bpermute addr: src group 2(g&1)
    const int a1 = a0 + 64;                  // src group 2(g&1)+1
    const bool sel = (g >> 1) != 0;
    const int w = blockIdx.x * 8 + wid;

    for (int it = 0; it < 8; ++it) {
        int tile = w + NWAVES * it;
        if (tile >= NTILES) break;
        const int p0 = tile * 32;

        // ---- passthrough copies for this tile (coalesced) ----
        out[3 * p0 + lane] = rays[3 * p0 + lane];
        if (lane < 32) out[3 * p0 + 64 + lane] = rays[3 * p0 + 64 + lane];
        out[3 * NPTS + 4 * p0 + lane] = rot[4 * p0 + lane];
        out[3 * NPTS + 4 * p0 + 64 + lane] = rot[4 * p0 + 64 + lane];
        if (lane < 32) out[7 * NPTS + p0 + lane] = h_e[2 * (p0 + lane)];

        // ---- gather -> act1 frags (B-layout: k=feature 8g+j, n=point c) ----
        bfx8 act1[2];
#pragma unroll
        for (int pt = 0; pt < 2; ++pt) {
            int p = p0 + pt * 16 + c;
            float px = rays[p * 3 + 0], py = rays[p * 3 + 1], pz = rays[p * 3 + 2];
            const float inv = 0.625f;
            float xn = fminf(fmaxf(px * inv, -1.f), 1.f) * 0.5f + 0.5f;
            float yn = fminf(fmaxf(py * inv, -1.f), 1.f) * 0.5f + 0.5f;
            float zn = fminf(fmaxf(pz * inv, -1.f), 1.f) * 0.5f + 0.5f;
            float tt = fminf(fmaxf(tme[p], 0.f), 1.f);
            float c4[4] = {xn, yn, zn, tt};
            int i0[4];
            float fr[4];
#pragma unroll
            for (int cc = 0; cc < 4; ++cc) {
                float x = c4[cc] * 127.0f;
                float xf = fminf(floorf(x), 126.0f);
                i0[cc] = (int)xf;
                fr[cc] = x - xf;
            }
            const int uc[6] = {0, 0, 1, 0, 1, 2};
            const int vc[6] = {1, 2, 2, 3, 3, 3};
            __half2 g2[4];
#pragma unroll
            for (int pl = 0; pl < 6; ++pl) {
                int x0 = i0[uc[pl]], y0 = i0[vc[pl]];
                float fx = fr[uc[pl]], fy = fr[vc[pl]];
                const __half* base = ph + (size_t)pl * PLSZ + ((y0 * RPLANE + x0) << 5) + (g << 3);
                uint4 q00 = *(const uint4*)base;
                uint4 q01 = *(const uint4*)(base + FDIM);
                uint4 q10 = *(const uint4*)(base + RPLANE * FDIM);
                uint4 q11 = *(const uint4*)(base + RPLANE * FDIM + FDIM);
                __half2 wa = __float2half2_rn((1.f - fx) * (1.f - fy));
                __half2 wb = __float2half2_rn(fx * (1.f - fy));
                __half2 wc = __float2half2_rn((1.f - fx) * fy);
                __half2 wd = __float2half2_rn(fx * fy);
                unsigned qa[4] = {q00.x, q00.y, q00.z, q00.w};
                unsigned qb[4] = {q01.x, q01.y, q01.z, q01.w};
                unsigned qc[4] = {q10.x, q10.y, q10.z, q10.w};
                unsigned qd[4] = {q11.x, q11.y, q11.z, q11.w};
#pragma unroll
                for (int i = 0; i < 4; ++i) {
                    __half2 r = __hmul2(u2h(qa[i]), wa);
                    r = __hfma2(u2h(qb[i]), wb, r);
                    r = __hfma2(u2h(qc[i]), wc, r);
                    r = __hfma2(u2h(qd[i]), wd, r);
                    g2[i] = (pl == 0) ? r : __hmul2(g2[i], r);
                }
            }
            uint4 av;
            {
                float2 v0 = __half22float2(g2[0]);
                float2 v1 = __half22float2(g2[1]);
                float2 v2 = __half22float2(g2[2]);
                float2 v3 = __half22float2(g2[3]);
                av.x = pk2(v0.x, v0.y);
                av.y = pk2(v1.x, v1.y);
                av.z = pk2(v2.x, v2.y);
                av.w = pk2(v3.x, v3.y);
            }
            act1[pt] = asfrag(av);
        }

        // ---- layer 1: wenc frags from global (L1-hot); convD -> act2 ----
        uint4 act2[2][8];
        {
            unsigned stE[2][2];
#pragma unroll
            for (int ct = 0; ct < 16; ++ct) {
                uint4 cur = *(const uint4*)(wf + (size_t)ct * 512 + lane * 8);
                float4 b4 = *(const float4*)(benc + 16 * ct + 4 * g);
                float bb[4] = {b4.x, b4.y, b4.z, b4.w};
#pragma unroll
                for (int pt = 0; pt < 2; ++pt) {
                    f32x4 z = {0.f, 0.f, 0.f, 0.f};
                    f32x4 d = __builtin_amdgcn_mfma_f32_16x16x32_bf16(asfrag(cur), act1[pt], z, 0, 0, 0);
                    float v0 = fmaxf(d[0] + bb[0], 0.f);
                    float v1 = fmaxf(d[1] + bb[1], 0.f);
                    float v2 = fmaxf(d[2] + bb[2], 0.f);
                    float v3 = fmaxf(d[3] + bb[3], 0.f);
                    unsigned Q0 = pk2(v0, v1), Q1 = pk2(v2, v3);
                    if ((ct & 1) == 0) {
                        stE[pt][0] = Q0; stE[pt][1] = Q1;
                    } else {
                        act2[pt][ct >> 1] = convD(stE[pt][0], stE[pt][1], Q0, Q1, a0, a1, sel);
                    }
                }
            }
        }

        // ---- layer 2: w1 frags from LDS; convD -> act3 ----
        uint4 act3[2][8];
        {
            unsigned stE[2][2];
#pragma unroll
            for (int ct = 0; ct < 16; ++ct) {
                uint4 wv[8];
#pragma unroll
                for (int ks = 0; ks < 8; ++ks)
                    wv[ks] = *(const uint4*)&wlds[(ct * 8 + ks) * 512 + lane * 8];
                float4 b4 = *(const float4*)(b1v + 16 * ct + 4 * g);
                float bb[4] = {b4.x, b4.y, b4.z, b4.w};
#pragma unroll
                for (int pt = 0; pt < 2; ++pt) {
                    f32x4 acc = {0.f, 0.f, 0.f, 0.f};
#pragma unroll
                    for (int ks = 0; ks < 8; ++ks)
                        acc = __builtin_amdgcn_mfma_f32_16x16x32_bf16(asfrag(wv[ks]), asfrag(act2[pt][ks]), acc, 0, 0, 0);
                    float v0 = fmaxf(acc[0] + bb[0], 0.f);
                    float v1 = fmaxf(acc[1] + bb[1], 0.f);
                    float v2 = fmaxf(acc[2] + bb[2], 0.f);
                    float v3 = fmaxf(acc[3] + bb[3], 0.f);
                    unsigned Q0 = pk2(v0, v1), Q1 = pk2(v2, v3);
                    if ((ct & 1) == 0) {
                        stE[pt][0] = Q0; stE[pt][1] = Q1;
                    } else {
                        act3[pt][ct >> 1] = convD(stE[pt][0], stE[pt][1], Q0, Q1, a0, a1, sel);
                    }
                }
            }
        }

        // ---- layer 3: w2 frags from LDS; D[pt][outcol]; + b2 + shs -> out ----
        {
#pragma unroll
            for (int ct = 0; ct < 3; ++ct) {
                uint4 wl[8];
#pragma unroll
                for (int ks = 0; ks < 8; ++ks)
                    wl[ks] = *(const uint4*)&wlds[65536 + (ct * 8 + ks) * 512 + lane * 8];
                float bias = b2v[16 * ct + c];
#pragma unroll
                for (int pt = 0; pt < 2; ++pt) {
                    f32x4 acc = {0.f, 0.f, 0.f, 0.f};
#pragma unroll
                    for (int ks = 0; ks < 8; ++ks)
                        acc = __builtin_amdgcn_mfma_f32_16x16x32_bf16(asfrag(act3[pt][ks]), asfrag(wl[ks]), acc, 0, 0, 0);
#pragma unroll
                    for (int r = 0; r < 4; ++r) {
                        int p = p0 + pt * 16 + 4 * g + r;
                        size_t idx = (size_t)p * 48 + 16 * ct + c;
                        out[(size_t)NPTS * 8 + idx] = shs[idx] + acc[r] + bias;
                    }
                }
            }
        }
    }
}

extern "C" void kernel_launch(void* const* d_in, const int* in_sizes, int n_in,
                              void* d_out, int out_size, void* d_ws, size_t ws_size,
                              hipStream_t stream) {
    const float* rays = (const float*)d_in[0];
    const float* rot  = (const float*)d_in[1];
    const float* shs  = (const float*)d_in[3];
    const float* tme  = (const float*)d_in[5];
    const float* h_e  = (const float*)d_in[6];
    const float* spf  = (const float*)d_in[7];
    const float* tpf  = (const float*)d_in[8];
    const float* wenc = (const float*)d_in[9];
    const float* benc = (const float*)d_in[10];
    const float* w1   = (const float*)d_in[11];
    const float* b1v  = (const float*)d_in[12];
    const float* w2   = (const float*)d_in[13];
    const float* b2v  = (const float*)d_in[14];
    float* out = (float*)d_out;
    unsigned short* wf = (unsigned short*)d_ws;    // 86016 shorts of weight frags
    __half* ph = (__half*)(wf + 86016);            // 6*PLSZ fp16 plane cache (~6.3 MB)

    prep2<<<2048, 256, 0, stream>>>(wenc, w1, w2, spf, tpf, wf, ph);
    fused7<<<256, 512, 0, stream>>>(rays, tme, rot, h_e, shs, ph, wf,
                                    benc, b1v, b2v, out);
}